// Round 2
// baseline (224.136 us; speedup 1.0000x reference)
//
#include <hip/hip_runtime.h>

// Problem constants (from reference): V=50000, D=512, B=8192, C=32, SIGMA=1
#define DIM     512
#define BATCH   8192
#define CTX     32
#define WPB     4               // waves per block
#define NTHREAD (WPB * 64)

// One WAVE per batch row b. Lane owns 8 floats of D as two contiguous float4
// slices: floats [lane*4, lane*4+4) and [256 + lane*4, 256 + lane*4 + 4).
// Online loop over the 32 context rows:
//   load row (once!) -> dist partial -> 6-step shfl_xor wave reduce ->
//   w = expf(-dist/2) -> acc += w*x, wsum += w
// Normalize at the end. No LDS, no barriers, rows fetched exactly once.
__global__ __launch_bounds__(NTHREAD, 6) void kembed_kernel(
    const int* __restrict__ context,   // [B, C]
    const int* __restrict__ center,    // [B]
    const float* __restrict__ W,       // [V, D]
    float* __restrict__ out)           // [B, D]
{
    const int lane = threadIdx.x & 63;
    const int b    = blockIdx.x * WPB + (threadIdx.x >> 6);  // row for this wave

    // All 32 context indices live in lanes 0..31 (dup in 32..63); readlane
    // later gives a wave-uniform (SGPR) index per c.
    const int myidx = context[b * CTX + (lane & 31)];

    const int cenIdx = __builtin_amdgcn_readfirstlane(center[b]);

    const float4* __restrict__ Wv = (const float4*)W;
    const size_t cbase = (size_t)cenIdx * (DIM / 4);
    const float4 cen0 = Wv[cbase + lane];
    const float4 cen1 = Wv[cbase + 64 + lane];

    float4 acc0 = make_float4(0.f, 0.f, 0.f, 0.f);
    float4 acc1 = make_float4(0.f, 0.f, 0.f, 0.f);
    float  wsum = 0.f;

#pragma unroll
    for (int c = 0; c < CTX; ++c) {
        const int idx = __builtin_amdgcn_readlane(myidx, c);  // scalar base
        const size_t rbase = (size_t)idx * (DIM / 4);
        const float4 x0 = Wv[rbase + lane];
        const float4 x1 = Wv[rbase + 64 + lane];

        float dx, d;
        dx = x0.x - cen0.x; d  = dx * dx;
        dx = x0.y - cen0.y; d += dx * dx;
        dx = x0.z - cen0.z; d += dx * dx;
        dx = x0.w - cen0.w; d += dx * dx;
        dx = x1.x - cen1.x; d += dx * dx;
        dx = x1.y - cen1.y; d += dx * dx;
        dx = x1.z - cen1.z; d += dx * dx;
        dx = x1.w - cen1.w; d += dx * dx;

#pragma unroll
        for (int off = 32; off >= 1; off >>= 1)
            d += __shfl_xor(d, off, 64);

        const float w = __expf(-0.5f * d);
        wsum += w;
        acc0.x += w * x0.x; acc0.y += w * x0.y;
        acc0.z += w * x0.z; acc0.w += w * x0.w;
        acc1.x += w * x1.x; acc1.y += w * x1.y;
        acc1.z += w * x1.z; acc1.w += w * x1.w;
    }

    const float inv = 1.0f / (wsum + 1e-8f);
    float4 o0, o1;
    o0.x = acc0.x * inv; o0.y = acc0.y * inv;
    o0.z = acc0.z * inv; o0.w = acc0.w * inv;
    o1.x = acc1.x * inv; o1.y = acc1.y * inv;
    o1.z = acc1.z * inv; o1.w = acc1.w * inv;

    float4* outv = (float4*)out;
    const size_t obase = (size_t)b * (DIM / 4);
    outv[obase + lane]      = o0;
    outv[obase + 64 + lane] = o1;
}

extern "C" void kernel_launch(void* const* d_in, const int* in_sizes, int n_in,
                              void* d_out, int out_size, void* d_ws, size_t ws_size,
                              hipStream_t stream) {
    const int*   context = (const int*)d_in[0];   // [B, C] int32
    const int*   center  = (const int*)d_in[1];   // [B] int32
    const float* W       = (const float*)d_in[2]; // [V, D] fp32
    float*       out     = (float*)d_out;         // [B, D] fp32

    kembed_kernel<<<BATCH / WPB, NTHREAD, 0, stream>>>(context, center, W, out);
}

// Round 3
// 144.709 us; speedup vs baseline: 1.5489x; 1.5489x over previous
//
#include <hip/hip_runtime.h>

// Problem constants (from reference): V=50000, D=512, B=8192, C=32, SIGMA=1
#define DIM     512
#define BATCH   8192
#define CTX     32
#define WPB     4
#define NTHREAD (WPB * 64)

// Branch-and-bound screen: partial dist over first 64 dims is a LOWER bound
// on the full distance. If partial > PROBE_THRESH, then
// w = exp(-dist/2) <= exp(-35) ~ 6e-16; with the reference's +1e-8 denominator
// floor, dropping such terms changes the output by < 1e-5 (threshold 6.6e-2).
// In fp32 the reference's own weight underflows to exactly 0 for these pairs.
// Pairs that pass the probe get the FULL exact computation (collisions pass
// with partial=0 and get w=1). Correctness does not depend on the data
// distribution — only performance does.
#define PROBE_THRESH 70.0f

// One WAVE per batch row. Four 16-lane groups; group g screens context slots
// c = g*8+i, i=0..7, reading only the first 256 B (64 dims) of each row.
// Survivors (rare, wave-uniform scalar mask) get full 512-dim treatment.
__global__ __launch_bounds__(NTHREAD, 6) void kembed_kernel(
    const int* __restrict__ context,   // [B, C]
    const int* __restrict__ center,    // [B]
    const float* __restrict__ W,       // [V, D]
    float* __restrict__ out)           // [B, D]
{
    const int tid  = threadIdx.x;
    const int lane = tid & 63;
    const int b    = blockIdx.x * WPB + (tid >> 6);
    const int g    = lane >> 4;        // 16-lane group id, 0..3
    const int gl   = lane & 15;        // lane within group

    const float4* __restrict__ Wv = (const float4*)W;

    // lane (c & 31) holds context index c
    const int myidx  = context[b * CTX + (lane & 31)];
    const int cenIdx = __builtin_amdgcn_readfirstlane(center[b]);
    const int cb     = cenIdx * (DIM / 4);

    // center's probe chunk: dims [4*gl, 4*gl+4)  (same 256 B for all groups)
    const float4 cp = Wv[cb + gl];

    // ---------------- probe phase ----------------
    unsigned int smask = 0;   // survivor bitmask over c = 0..31 (wave-uniform)
#pragma unroll
    for (int i = 0; i < 8; ++i) {
        const int c   = g * 8 + i;
        const int idx = __shfl(myidx, c, 64);             // uniform per group
        const float4 xp = Wv[(size_t)idx * (DIM / 4) + gl];

        float dx, p;
        dx = xp.x - cp.x; p  = dx * dx;
        dx = xp.y - cp.y; p += dx * dx;
        dx = xp.z - cp.z; p += dx * dx;
        dx = xp.w - cp.w; p += dx * dx;
        // reduce over the 16-lane group
        p += __shfl_xor(p, 1, 64);
        p += __shfl_xor(p, 2, 64);
        p += __shfl_xor(p, 4, 64);
        p += __shfl_xor(p, 8, 64);

        const unsigned long long m = __ballot(p < PROBE_THRESH);
        // group g's verdict sits (replicated) at bit g*16
        smask |= (unsigned int)((m >>  0) & 1ull) << (0 * 8 + i);
        smask |= (unsigned int)((m >> 16) & 1ull) << (1 * 8 + i);
        smask |= (unsigned int)((m >> 32) & 1ull) << (2 * 8 + i);
        smask |= (unsigned int)((m >> 48) & 1ull) << (3 * 8 + i);
    }

    float4 acc0 = make_float4(0.f, 0.f, 0.f, 0.f);
    float4 acc1 = make_float4(0.f, 0.f, 0.f, 0.f);
    float  wsum = 0.f;

    // ---------------- survivor phase (rare, wave-uniform) ----------------
    if (smask) {
        const float4 c0 = Wv[cb + lane];
        const float4 c1 = Wv[cb + 64 + lane];
        while (smask) {
            const int c = (int)__builtin_ctz(smask);
            smask &= smask - 1;
            const int idx = __builtin_amdgcn_readlane(myidx, c);
            const size_t rb = (size_t)idx * (DIM / 4);
            const float4 x0 = Wv[rb + lane];
            const float4 x1 = Wv[rb + 64 + lane];

            float dx, d;
            dx = x0.x - c0.x; d  = dx * dx;
            dx = x0.y - c0.y; d += dx * dx;
            dx = x0.z - c0.z; d += dx * dx;
            dx = x0.w - c0.w; d += dx * dx;
            dx = x1.x - c1.x; d += dx * dx;
            dx = x1.y - c1.y; d += dx * dx;
            dx = x1.z - c1.z; d += dx * dx;
            dx = x1.w - c1.w; d += dx * dx;
#pragma unroll
            for (int off = 32; off >= 1; off >>= 1)
                d += __shfl_xor(d, off, 64);

            const float w = __expf(-0.5f * d);   // collision: d==0 -> w==1
            wsum += w;
            acc0.x += w * x0.x; acc0.y += w * x0.y;
            acc0.z += w * x0.z; acc0.w += w * x0.w;
            acc1.x += w * x1.x; acc1.y += w * x1.y;
            acc1.z += w * x1.z; acc1.w += w * x1.w;
        }
    }

    const float inv = 1.0f / (wsum + 1e-8f);
    float4 o0, o1;
    o0.x = acc0.x * inv; o0.y = acc0.y * inv;
    o0.z = acc0.z * inv; o0.w = acc0.w * inv;
    o1.x = acc1.x * inv; o1.y = acc1.y * inv;
    o1.z = acc1.z * inv; o1.w = acc1.w * inv;

    float4* outv = (float4*)out;
    const size_t ob = (size_t)b * (DIM / 4);
    outv[ob + lane]      = o0;
    outv[ob + 64 + lane] = o1;
}

extern "C" void kernel_launch(void* const* d_in, const int* in_sizes, int n_in,
                              void* d_out, int out_size, void* d_ws, size_t ws_size,
                              hipStream_t stream) {
    const int*   context = (const int*)d_in[0];   // [B, C] int32
    const int*   center  = (const int*)d_in[1];   // [B] int32
    const float* W       = (const float*)d_in[2]; // [V, D] fp32
    float*       out     = (float*)d_out;         // [B, D] fp32

    kembed_kernel<<<BATCH / WPB, NTHREAD, 0, stream>>>(context, center, W, out);
}

// Round 5
// 144.575 us; speedup vs baseline: 1.5503x; 1.0009x over previous
//
#include <hip/hip_runtime.h>

// Problem constants (from reference): V=50000, D=512, B=8192, C=32, SIGMA=1
#define DIM     512
#define BATCH   8192
#define CTX     32
#define WPB     4
#define NTHREAD (WPB * 64)

// Branch-and-bound screen: the partial distance over the first 64 dims is a
// LOWER bound on the full 512-dim distance. If partial > PROBE_THRESH then
// w = exp(-dist/2) <= exp(-35) ~ 6e-16; with the reference's +1e-8 denominator
// floor, dropping such pairs perturbs the output by < 1e-5 (threshold 6.6e-2).
// In fp32 the reference's own weight underflows to exactly 0 for these pairs
// anyway (observed absmax 0.0). Pairs that pass get the FULL exact
// computation (index collisions pass with partial=0 and get w=1).
// Correctness does not depend on the data distribution — only speed does.
#define PROBE_THRESH 70.0f

// Native clang vector type for nontemporal stores (the builtin rejects
// HIP_vector_type structs).
typedef float nt_float4 __attribute__((ext_vector_type(4)));

// One WAVE per batch row. Four 16-lane groups; group g screens context slots
// c = g*8+i, i=0..7, reading only the first 256 B (64 dims) of each row.
// No cross-lane index shuffles: lane loads its group's index for iteration i
// directly (transposed read of context, broadcast within the group).
// No per-iteration ballots: group-uniform verdict bits accumulate in a
// per-lane byte; 4 readlanes build the wave-uniform survivor mask at the end.
__global__ __launch_bounds__(NTHREAD, 6) void kembed_kernel(
    const int* __restrict__ context,   // [B, C]
    const int* __restrict__ center,    // [B]
    const float* __restrict__ W,       // [V, D]
    float* __restrict__ out)           // [B, D]
{
    const int tid  = threadIdx.x;
    const int lane = tid & 63;
    const int b    = blockIdx.x * WPB + (tid >> 6);
    const int g    = lane >> 4;        // 16-lane group id, 0..3
    const int gl   = lane & 15;        // lane within group

    const float4* __restrict__ Wv = (const float4*)W;

    // Transposed index loads: iteration i wants lane to hold index of row
    // c = g*8 + i. All 8 come from one 128 B line; issued up-front.
    int tix[8];
#pragma unroll
    for (int i = 0; i < 8; ++i)
        tix[i] = context[b * CTX + g * 8 + i];

    // Also keep the lane-major copy for the (rare) survivor phase.
    const int myidx  = context[b * CTX + (lane & 31)];
    const int cenIdx = __builtin_amdgcn_readfirstlane(center[b]);
    const int cb     = cenIdx * (DIM / 4);

    // center's probe chunk: dims [4*gl, 4*gl+4)  (same 256 B for all groups)
    const float4 cp = Wv[cb + gl];

    // ---------------- probe phase ----------------
    int vb = 0;   // verdict byte: bit i = row g*8+i survives (group-uniform)
#pragma unroll
    for (int i = 0; i < 8; ++i) {
        const float4 xp = Wv[(size_t)tix[i] * (DIM / 4) + gl];

        float dx, p;
        dx = xp.x - cp.x; p  = dx * dx;
        dx = xp.y - cp.y; p += dx * dx;
        dx = xp.z - cp.z; p += dx * dx;
        dx = xp.w - cp.w; p += dx * dx;
        // reduce over the 16-lane group
        p += __shfl_xor(p, 1, 64);
        p += __shfl_xor(p, 2, 64);
        p += __shfl_xor(p, 4, 64);
        p += __shfl_xor(p, 8, 64);

        vb |= (p < PROBE_THRESH) ? (1 << i) : 0;
    }

    // Wave-uniform survivor bitmask over c = 0..31: byte g = group g verdicts.
    unsigned int smask =
        ((unsigned int)__builtin_amdgcn_readlane(vb,  0)      ) |
        ((unsigned int)__builtin_amdgcn_readlane(vb, 16) <<  8) |
        ((unsigned int)__builtin_amdgcn_readlane(vb, 32) << 16) |
        ((unsigned int)__builtin_amdgcn_readlane(vb, 48) << 24);

    float4 acc0 = make_float4(0.f, 0.f, 0.f, 0.f);
    float4 acc1 = make_float4(0.f, 0.f, 0.f, 0.f);
    float  wsum = 0.f;

    // ---------------- survivor phase (rare, wave-uniform) ----------------
    if (smask) {
        const float4 c0 = Wv[cb + lane];
        const float4 c1 = Wv[cb + 64 + lane];
        while (smask) {
            const int c = (int)__builtin_ctz(smask);
            smask &= smask - 1;
            const int idx = __builtin_amdgcn_readlane(myidx, c);
            const size_t rb = (size_t)idx * (DIM / 4);
            const float4 x0 = Wv[rb + lane];
            const float4 x1 = Wv[rb + 64 + lane];

            float dx, d;
            dx = x0.x - c0.x; d  = dx * dx;
            dx = x0.y - c0.y; d += dx * dx;
            dx = x0.z - c0.z; d += dx * dx;
            dx = x0.w - c0.w; d += dx * dx;
            dx = x1.x - c1.x; d += dx * dx;
            dx = x1.y - c1.y; d += dx * dx;
            dx = x1.z - c1.z; d += dx * dx;
            dx = x1.w - c1.w; d += dx * dx;
#pragma unroll
            for (int off = 32; off >= 1; off >>= 1)
                d += __shfl_xor(d, off, 64);

            const float w = __expf(-0.5f * d);   // collision: d==0 -> w==1
            wsum += w;
            acc0.x += w * x0.x; acc0.y += w * x0.y;
            acc0.z += w * x0.z; acc0.w += w * x0.w;
            acc1.x += w * x1.x; acc1.y += w * x1.y;
            acc1.z += w * x1.z; acc1.w += w * x1.w;
        }
    }

    const float inv = 1.0f / (wsum + 1e-8f);
    nt_float4 o0, o1;
    o0.x = acc0.x * inv; o0.y = acc0.y * inv;
    o0.z = acc0.z * inv; o0.w = acc0.w * inv;
    o1.x = acc1.x * inv; o1.y = acc1.y * inv;
    o1.z = acc1.z * inv; o1.w = acc1.w * inv;

    // Streaming output (16 MB, no reuse) — nontemporal keeps it out of L2 so
    // the probe region stays resident.
    nt_float4* outv = (nt_float4*)out;
    const size_t ob = (size_t)b * (DIM / 4);
    __builtin_nontemporal_store(o0, &outv[ob + lane]);
    __builtin_nontemporal_store(o1, &outv[ob + 64 + lane]);
}

extern "C" void kernel_launch(void* const* d_in, const int* in_sizes, int n_in,
                              void* d_out, int out_size, void* d_ws, size_t ws_size,
                              hipStream_t stream) {
    const int*   context = (const int*)d_in[0];   // [B, C] int32
    const int*   center  = (const int*)d_in[1];   // [B] int32
    const float* W       = (const float*)d_in[2]; // [V, D] fp32
    float*       out     = (float*)d_out;         // [B, D] fp32

    kembed_kernel<<<BATCH / WPB, NTHREAD, 0, stream>>>(context, center, W, out);
}